// Round 2
// baseline (1081.682 us; speedup 1.0000x reference)
//
#include <hip/hip_runtime.h>

#define S2CAP 24576   // cap on |S2| (robots + sources of robot in-edges); expected ~17.4K
#define ECAP  524288  // cap on filtered layer-1 edge count; expected ~292K

__device__ __forceinline__ float fsig(float x){ return 1.f/(1.f + __expf(-x)); }
__device__ __forceinline__ float ftanh(float a){
  a = fminf(fmaxf(a, -15.f), 15.f);
  float e2 = __expf(2.f*a);
  return (e2 - 1.f)/(e2 + 1.f);
}
__device__ __forceinline__ float attw(float e){        // leaky_relu(0.2) then exp (no max-sub)
  e = (e > 0.f) ? e : 0.2f*e;
  return __expf(e);
}

// ---- fused init: AsAd precompute + robot flag + cnt1 zero + ctrl ----
// (sidx was memset to -1 earlier in the stream)
__global__ void k_init(const float* __restrict__ c1W, const float* __restrict__ c1as,
                       const float* __restrict__ c1ad, float* __restrict__ AsAd,
                       const int* __restrict__ rix, int B, int* __restrict__ sidx,
                       int* __restrict__ nodeof, int* __restrict__ ctrl,
                       int* __restrict__ cnt1){
  int gid = blockIdx.x*blockDim.x + threadIdx.x;
  if (gid == 0) ctrl[0] = B;
  if (gid < 48){
    int which = gid/24, r = gid%24, k = r/6, h = r%6;
    const float* av = which ? c1ad : c1as;
    float s = 0.f;
    for (int f = 0; f < 16; ++f) s += c1W[(h*16+f)*4 + k] * av[h*16+f];
    AsAd[which*24 + k*6 + h] = s;
  }
  if (gid < B){ int r = rix[gid]; sidx[r] = gid; nodeof[gid] = r; }
  if (gid < S2CAP) cnt1[gid] = 0;
}

// ---- scan 1: claim sources of edges into robots ----
__global__ void k_claim(const int* __restrict__ ei, int E, int B,
                        int* __restrict__ sidx, int* __restrict__ nodeof,
                        int* __restrict__ ctrl){
  int e = blockIdx.x*blockDim.x + threadIdx.x;
  if (e >= E) return;
  int d = ei[E + e];
  int sd = sidx[d];
  if (sd < 0 || sd >= B) return;           // dst not a robot
  int s = ei[e];
  if (sidx[s] < 0){
    int old = atomicCAS(&sidx[s], -1, -2);
    if (old == -1){
      int id = atomicAdd(&ctrl[0], 1);
      if (id < S2CAP){ nodeof[id] = s; sidx[s] = id; }
      else sidx[s] = -1;                    // overflow (won't happen at these sizes)
    }
  }
}

// ---- scan 2: count in-edges of S2 nodes ----
__global__ void k_count(const int* __restrict__ ei, int E,
                        const int* __restrict__ sidx, int* __restrict__ cnt1){
  int e = blockIdx.x*blockDim.x + threadIdx.x;
  if (e >= E) return;
  int sd = sidx[ei[E + e]];
  if (sd >= 0) atomicAdd(&cnt1[sd], 1);
}

// ---- single-block exclusive scan over cnt1 ----
__global__ void k_scan(const int* __restrict__ cnt, int* __restrict__ off,
                       int* __restrict__ run, int n){
  __shared__ int part[1024];
  int tid = threadIdx.x;
  int per = (n + 1023)/1024;
  int base = tid*per;
  int s = 0;
  for (int i = 0; i < per; ++i){ int idx = base+i; if (idx < n) s += cnt[idx]; }
  part[tid] = s; __syncthreads();
  for (int d = 1; d < 1024; d <<= 1){
    int v = part[tid];
    int o = (tid >= d) ? part[tid-d] : 0;
    __syncthreads();
    part[tid] = v + o;
    __syncthreads();
  }
  int acc = (tid == 0) ? 0 : part[tid-1];
  for (int i = 0; i < per; ++i){
    int idx = base+i;
    if (idx < n){ off[idx] = acc; run[idx] = acc; acc += cnt[idx]; }
  }
}

// ---- scan 3: scatter sources into subset CSR ----
__global__ void k_scatter(const int* __restrict__ ei, int E,
                          const int* __restrict__ sidx, int* __restrict__ run1,
                          int* __restrict__ csr1){
  int e = blockIdx.x*blockDim.x + threadIdx.x;
  if (e >= E) return;
  int sd = sidx[ei[E + e]];
  if (sd >= 0){
    int p = atomicAdd(&run1[sd], 1);
    if (p < ECAP) csr1[p] = ei[e];
  }
}

// ---- layer-1 GAT agg at S2 nodes, per (node, head); writes tanh(agg/den + b) ----
__global__ void k_gat1(const float* __restrict__ x, const float* __restrict__ c1W,
                       const float* __restrict__ c1b, const float* __restrict__ AsAd,
                       const int* __restrict__ nodeof, const int* __restrict__ off1,
                       const int* __restrict__ cnt1, const int* __restrict__ csr1,
                       const int* __restrict__ ctrl, float* __restrict__ tbuf){
  int gid = blockIdx.x*blockDim.x + threadIdx.x;
  int sid = gid/6, h = gid - sid*6;
  if (sid >= ctrl[0]) return;
  float Ask[4], Adk[4];
  #pragma unroll
  for (int k = 0; k < 4; ++k){ Ask[k] = AsAd[k*6+h]; Adk[k] = AsAd[24 + k*6 + h]; }
  float W[16][4];
  #pragma unroll
  for (int f = 0; f < 16; ++f)
    #pragma unroll
    for (int k = 0; k < 4; ++k) W[f][k] = c1W[(h*16+f)*4 + k];
  int d = nodeof[sid];
  float4 xd = *(const float4*)(x + 4*(size_t)d);
  float ad = xd.x*Adk[0] + xd.y*Adk[1] + xd.z*Adk[2] + xd.w*Adk[3];
  int beg = off1[sid], n = cnt1[sid];
  if (beg >= ECAP) n = 0; else if (beg + n > ECAP) n = ECAP - beg;
  float den = 0.f, agg[16];
  #pragma unroll
  for (int f = 0; f < 16; ++f) agg[f] = 0.f;
  for (int j = -1; j < n; ++j){            // j==-1: self loop
    int s = (j < 0) ? d : csr1[beg + j];
    float4 xv = *(const float4*)(x + 4*(size_t)s);
    float as = xv.x*Ask[0] + xv.y*Ask[1] + xv.z*Ask[2] + xv.w*Ask[3];
    float wgt = attw(as + ad);
    den += wgt;
    #pragma unroll
    for (int f = 0; f < 16; ++f){
      float h1 = xv.x*W[f][0] + xv.y*W[f][1] + xv.z*W[f][2] + xv.w*W[f][3];
      agg[f] = fmaf(wgt, h1, agg[f]);
    }
  }
  float inv = 1.f/den;
  #pragma unroll
  for (int f = 0; f < 16; ++f)
    tbuf[(size_t)sid*96 + h*16 + f] = ftanh(agg[f]*inv + c1b[h*16+f]);
}

// ---- layer-2 linear + attention scalars fused (32-lane shfl reduce) ----
__global__ void k_h2att(const float* __restrict__ c2W, const float* __restrict__ tbuf,
                        const float* __restrict__ c2as, const float* __restrict__ c2ad,
                        const int* __restrict__ ctrl, float* __restrict__ h2,
                        float* __restrict__ as2, float* __restrict__ ad2){
  int gid = blockIdx.x*blockDim.x + threadIdx.x;
  int sid = gid >> 5, o = gid & 31;
  bool act = sid < ctrl[0];
  float s = 0.f;
  if (act){
    const float* t = tbuf + (size_t)sid*96;
    const float* wr = c2W + o*96;
    #pragma unroll
    for (int j = 0; j < 96; ++j) s = fmaf(wr[j], t[j], s);
    h2[(size_t)sid*32 + o] = s;
  }
  float a = act ? s*c2as[o] : 0.f;
  float b = act ? s*c2ad[o] : 0.f;
  #pragma unroll
  for (int w = 16; w >= 1; w >>= 1){
    a += __shfl_xor(a, w, 32);
    b += __shfl_xor(b, w, 32);
  }
  if (act && o == 0){ as2[sid] = a; ad2[sid] = b; }
}

// ---- layer-2 GAT agg at robots + concat + fc1 + tanh ----
__global__ void k_gat2fc1(const float* __restrict__ h2, const float* __restrict__ as2,
                          const float* __restrict__ ad2, const float* __restrict__ c2b,
                          const float* __restrict__ rf, const float* __restrict__ fc1W,
                          const float* __restrict__ fc1b, const int* __restrict__ sidx,
                          const int* __restrict__ off1, const int* __restrict__ cnt1,
                          const int* __restrict__ csr1, float* __restrict__ xs, int B){
  int rp = blockIdx.x*blockDim.x + threadIdx.x;
  if (rp >= B) return;
  float ad = ad2[rp];
  float den = 0.f, agg[32];
  #pragma unroll
  for (int o = 0; o < 32; ++o) agg[o] = 0.f;
  int beg = off1[rp], n = cnt1[rp];
  if (beg >= ECAP) n = 0; else if (beg + n > ECAP) n = ECAP - beg;
  for (int j = -1; j < n; ++j){
    int ss;
    if (j < 0) ss = rp;                    // self loop (robot's own sid == rp)
    else { int s = csr1[beg + j]; ss = sidx[s]; if (ss < 0 || ss >= S2CAP) continue; }
    float wgt = attw(as2[ss] + ad);
    den += wgt;
    const float* hv = h2 + (size_t)ss*32;
    #pragma unroll
    for (int o = 0; o < 32; ++o) agg[o] = fmaf(wgt, hv[o], agg[o]);
  }
  float inv = 1.f/den;
  float cat[36];
  #pragma unroll
  for (int o = 0; o < 32; ++o) cat[o] = agg[o]*inv + c2b[o];
  #pragma unroll
  for (int k = 0; k < 4; ++k) cat[32+k] = rf[rp*4+k];
  for (int o = 0; o < 64; ++o){
    float s = fc1b[o];
    const float* wrow = fc1W + o*36;
    #pragma unroll
    for (int j = 0; j < 36; ++j) s = fmaf(wrow[j], cat[j], s);
    xs[(size_t)rp*64 + o] = ftanh(s);
  }
}

// ---- GRU input gates for all steps + whh transpose, fused ----
__global__ void k_giT(const float* __restrict__ xs, const float* __restrict__ wih,
                      const float* __restrict__ bih, const float* __restrict__ bhh,
                      float* __restrict__ gi, const float* __restrict__ whh,
                      float* __restrict__ whhT, int B){
  int gid = blockIdx.x*blockDim.x + threadIdx.x;
  int NGI = B*192;
  if (gid < NGI){
    int t = gid/192, g = gid - t*192;
    const float* xv = xs + (size_t)t*64;
    const float* wr = wih + (size_t)g*64;
    float s = bih[g] + (g < 128 ? bhh[g] : 0.f);
    #pragma unroll
    for (int k = 0; k < 64; ++k) s = fmaf(wr[k], xv[k], s);
    gi[gid] = s;
  } else {
    int q = gid - NGI;
    if (q < 192*64){
      int g = q >> 6, k = q & 63;
      whhT[k*192 + g] = whh[g*64 + k];
    }
  }
}

// ---- sequential GRU scan: single wave, weights pinned in VGPRs, h via readlane ----
__global__ __launch_bounds__(64) void k_gru(const float* __restrict__ gi,
                       const float* __restrict__ whhT, const float* __restrict__ bhh,
                       float* __restrict__ ys, int B){
  int u = threadIdx.x;
  float wr[64], wz[64], wn[64];
  #pragma unroll
  for (int k = 0; k < 64; ++k){
    wr[k] = whhT[k*192 + u];
    wz[k] = whhT[k*192 + 64 + u];
    wn[k] = whhT[k*192 + 128 + u];
  }
  // pin weights in VGPRs: compiler must not re-load them inside the loop
  #pragma unroll
  for (int k = 0; k < 64; ++k){
    asm volatile("" : "+v"(wr[k]), "+v"(wz[k]), "+v"(wn[k]));
  }
  float bn = bhh[128 + u];
  float hu = 0.f;
  float grc = gi[u], gzc = gi[64 + u], gnc = gi[128 + u];
  for (int t = 0; t < B; ++t){
    int tn = (t + 1 < B) ? t + 1 : t;
    float grn = gi[tn*192 + u], gzn = gi[tn*192 + 64 + u], gnn = gi[tn*192 + 128 + u];
    float ar0 = 0.f, ar1 = 0.f, az0 = 0.f, az1 = 0.f, an0 = bn, an1 = 0.f;
    #pragma unroll
    for (int k = 0; k < 64; k += 2){
      float h0 = __int_as_float(__builtin_amdgcn_readlane(__float_as_int(hu), k));
      float h1 = __int_as_float(__builtin_amdgcn_readlane(__float_as_int(hu), k + 1));
      ar0 = fmaf(wr[k],   h0, ar0);
      az0 = fmaf(wz[k],   h0, az0);
      an0 = fmaf(wn[k],   h0, an0);
      ar1 = fmaf(wr[k+1], h1, ar1);
      az1 = fmaf(wz[k+1], h1, az1);
      an1 = fmaf(wn[k+1], h1, an1);
    }
    float r  = fsig(grc + ar0 + ar1);
    float z  = fsig(gzc + az0 + az1);
    float ng = ftanh(gnc + r*(an0 + an1));
    hu = (1.f - z)*ng + z*hu;
    ys[(size_t)t*64 + u] = hu;
    grc = grn; gzc = gzn; gnc = gnn;
  }
}

// ---- final fc2 ----
__global__ void k_fc2(const float* __restrict__ ys, const float* __restrict__ f2W,
                      const float* __restrict__ f2b, float* __restrict__ out, int B){
  int gid = blockIdx.x*blockDim.x + threadIdx.x;
  if (gid >= B*11) return;
  int t = gid/11, a = gid - t*11;
  const float* hv = ys + (size_t)t*64;
  const float* wr = f2W + a*64;
  float s = f2b[a];
  #pragma unroll
  for (int k = 0; k < 64; ++k) s = fmaf(wr[k], hv[k], s);
  out[gid] = s;
}

extern "C" void kernel_launch(void* const* d_in, const int* in_sizes, int n_in,
                              void* d_out, int out_size, void* d_ws, size_t ws_size,
                              hipStream_t stream) {
  (void)n_in; (void)out_size; (void)ws_size;
  const float* x    = (const float*)d_in[0];
  const int*   ei   = (const int*)d_in[1];
  const int*   rix  = (const int*)d_in[2];
  const float* rf   = (const float*)d_in[3];
  const float* c1W  = (const float*)d_in[4];
  const float* c1as = (const float*)d_in[5];
  const float* c1ad = (const float*)d_in[6];
  const float* c1b  = (const float*)d_in[7];
  const float* c2W  = (const float*)d_in[8];
  const float* c2as = (const float*)d_in[9];
  const float* c2ad = (const float*)d_in[10];
  const float* c2b  = (const float*)d_in[11];
  const float* fc1W = (const float*)d_in[12];
  const float* fc1b = (const float*)d_in[13];
  const float* wih  = (const float*)d_in[14];
  const float* whh  = (const float*)d_in[15];
  const float* bih  = (const float*)d_in[16];
  const float* bhh  = (const float*)d_in[17];
  const float* f2W  = (const float*)d_in[18];
  const float* f2b  = (const float*)d_in[19];
  float* out = (float*)d_out;

  const int N = in_sizes[0]/4;
  const int E = in_sizes[1]/2;
  const int B = in_sizes[2];

  char* w = (char*)d_ws;
  size_t off = 0;
  auto take = [&](size_t bytes)->char*{
    char* p = w + off;
    off = (off + bytes + 255) & ~(size_t)255;
    return p;
  };
  int*   ctrl   = (int*)  take(256);
  float* AsAd   = (float*)take(256);
  int*   sidx   = (int*)  take((size_t)N*4);
  int*   nodeof = (int*)  take((size_t)S2CAP*4);
  int*   cnt1   = (int*)  take((size_t)S2CAP*4);
  int*   off1   = (int*)  take((size_t)S2CAP*4);
  int*   run1   = (int*)  take((size_t)S2CAP*4);
  int*   csr1   = (int*)  take((size_t)ECAP*4);
  float* tbuf   = (float*)take((size_t)S2CAP*96*4);
  float* h2     = (float*)take((size_t)S2CAP*32*4);
  float* as2    = (float*)take((size_t)S2CAP*4);
  float* ad2    = (float*)take((size_t)S2CAP*4);
  float* xs     = (float*)take((size_t)B*64*4);
  float* gi     = (float*)take((size_t)B*192*4);
  float* whhT   = (float*)take((size_t)192*64*4);
  float* ys     = (float*)take((size_t)B*64*4);

  hipMemsetAsync(sidx, 0xFF, (size_t)N*4, stream);       // -1

  k_init   <<<(S2CAP+255)/256, 256, 0, stream>>>(c1W, c1as, c1ad, AsAd, rix, B, sidx, nodeof, ctrl, cnt1);
  k_claim  <<<(E+255)/256, 256, 0, stream>>>(ei, E, B, sidx, nodeof, ctrl);
  k_count  <<<(E+255)/256, 256, 0, stream>>>(ei, E, sidx, cnt1);
  k_scan   <<<1, 1024, 0, stream>>>(cnt1, off1, run1, S2CAP);
  k_scatter<<<(E+255)/256, 256, 0, stream>>>(ei, E, sidx, run1, csr1);
  k_gat1   <<<(S2CAP*6+255)/256, 256, 0, stream>>>(x, c1W, c1b, AsAd, nodeof, off1, cnt1, csr1, ctrl, tbuf);
  k_h2att  <<<(S2CAP*32+255)/256, 256, 0, stream>>>(c2W, tbuf, c2as, c2ad, ctrl, h2, as2, ad2);
  k_gat2fc1<<<(B+255)/256, 256, 0, stream>>>(h2, as2, ad2, c2b, rf, fc1W, fc1b, sidx, off1, cnt1, csr1, xs, B);
  k_giT    <<<(B*192 + 192*64 + 255)/256, 256, 0, stream>>>(xs, wih, bih, bhh, gi, whh, whhT, B);
  k_gru    <<<1, 64, 0, stream>>>(gi, whhT, bhh, ys, B);
  k_fc2    <<<(B*11+255)/256, 256, 0, stream>>>(ys, f2W, f2b, out, B);
}

// Round 3
// 954.358 us; speedup vs baseline: 1.1334x; 1.1334x over previous
//
#include <hip/hip_runtime.h>

#define S2CAP 24576   // cap on |S2| (robots + sources of robot in-edges); expected ~17.4K
#define DEG   96      // padded per-node in-degree cap (Poisson(16): P(>96) ~ 1e-40)

__device__ __forceinline__ float fsig(float x){ return 1.f/(1.f + __expf(-x)); }
__device__ __forceinline__ float ftanh(float a){
  a = fminf(fmaxf(a, -15.f), 15.f);
  float e2 = __expf(2.f*a);
  return (e2 - 1.f)/(e2 + 1.f);
}
__device__ __forceinline__ float attw(float e){        // leaky_relu(0.2) then exp (no max-sub)
  e = (e > 0.f) ? e : 0.2f*e;
  return __expf(e);
}

// ---- fused init: AsAd precompute + robot flag + cnt1 zero + ctrl ----
// (sidx was memset to -1 earlier in the stream)
__global__ void k_init(const float* __restrict__ c1W, const float* __restrict__ c1as,
                       const float* __restrict__ c1ad, float* __restrict__ AsAd,
                       const int* __restrict__ rix, int B, int* __restrict__ sidx,
                       int* __restrict__ nodeof, int* __restrict__ ctrl,
                       int* __restrict__ cnt1){
  int gid = blockIdx.x*blockDim.x + threadIdx.x;
  if (gid == 0) ctrl[0] = B;
  if (gid < 48){
    int which = gid/24, r = gid%24, k = r/6, h = r%6;
    const float* av = which ? c1ad : c1as;
    float s = 0.f;
    for (int f = 0; f < 16; ++f) s += c1W[(h*16+f)*4 + k] * av[h*16+f];
    AsAd[which*24 + k*6 + h] = s;
  }
  if (gid < B){ int r = rix[gid]; sidx[r] = gid; nodeof[gid] = r; }
  if (gid < S2CAP) cnt1[gid] = 0;
}

// ---- scan 1: claim sources of edges into robots ----
__global__ void k_claim(const int* __restrict__ ei, int E, int B,
                        int* __restrict__ sidx, int* __restrict__ nodeof,
                        int* __restrict__ ctrl){
  int e = blockIdx.x*blockDim.x + threadIdx.x;
  if (e >= E) return;
  int d = ei[E + e];
  int sd = sidx[d];
  if (sd < 0 || sd >= B) return;           // dst not a robot
  int s = ei[e];
  if (sidx[s] < 0){
    int old = atomicCAS(&sidx[s], -1, -2);
    if (old == -1){
      int id = atomicAdd(&ctrl[0], 1);
      if (id < S2CAP){ nodeof[id] = s; sidx[s] = id; }
      else sidx[s] = -1;                    // overflow (won't happen at these sizes)
    }
  }
}

// ---- scan 2: scatter sources into fixed-stride padded CSR (no count/scan passes) ----
__global__ void k_scat(const int* __restrict__ ei, int E,
                       const int* __restrict__ sidx, int* __restrict__ cnt1,
                       int* __restrict__ csr1){
  int e = blockIdx.x*blockDim.x + threadIdx.x;
  if (e >= E) return;
  int sd = sidx[ei[E + e]];
  if (sd >= 0){
    int p = atomicAdd(&cnt1[sd], 1);
    if (p < DEG) csr1[sd*DEG + p] = ei[e];
  }
}

// ---- layer-1 GAT agg at S2 nodes, per (node, head); writes tanh(agg/den + b) ----
__global__ void k_gat1(const float* __restrict__ x, const float* __restrict__ c1W,
                       const float* __restrict__ c1b, const float* __restrict__ AsAd,
                       const int* __restrict__ nodeof, const int* __restrict__ cnt1,
                       const int* __restrict__ csr1, const int* __restrict__ ctrl,
                       float* __restrict__ tbuf){
  int gid = blockIdx.x*blockDim.x + threadIdx.x;
  int sid = gid/6, h = gid - sid*6;
  if (sid >= ctrl[0]) return;
  float Ask[4], Adk[4];
  #pragma unroll
  for (int k = 0; k < 4; ++k){ Ask[k] = AsAd[k*6+h]; Adk[k] = AsAd[24 + k*6 + h]; }
  float W[16][4];
  #pragma unroll
  for (int f = 0; f < 16; ++f)
    #pragma unroll
    for (int k = 0; k < 4; ++k) W[f][k] = c1W[(h*16+f)*4 + k];
  int d = nodeof[sid];
  float4 xd = *(const float4*)(x + 4*(size_t)d);
  float ad = xd.x*Adk[0] + xd.y*Adk[1] + xd.z*Adk[2] + xd.w*Adk[3];
  int beg = sid*DEG, n = cnt1[sid];
  n = (n < DEG) ? n : DEG;
  float den = 0.f, agg[16];
  #pragma unroll
  for (int f = 0; f < 16; ++f) agg[f] = 0.f;
  for (int j = -1; j < n; ++j){            // j==-1: self loop
    int s = (j < 0) ? d : csr1[beg + j];
    float4 xv = *(const float4*)(x + 4*(size_t)s);
    float as = xv.x*Ask[0] + xv.y*Ask[1] + xv.z*Ask[2] + xv.w*Ask[3];
    float wgt = attw(as + ad);
    den += wgt;
    #pragma unroll
    for (int f = 0; f < 16; ++f){
      float h1 = xv.x*W[f][0] + xv.y*W[f][1] + xv.z*W[f][2] + xv.w*W[f][3];
      agg[f] = fmaf(wgt, h1, agg[f]);
    }
  }
  float inv = 1.f/den;
  #pragma unroll
  for (int f = 0; f < 16; ++f)
    tbuf[(size_t)sid*96 + h*16 + f] = ftanh(agg[f]*inv + c1b[h*16+f]);
}

// ---- layer-2 linear + attention scalars fused (32-lane shfl reduce) ----
__global__ void k_h2att(const float* __restrict__ c2W, const float* __restrict__ tbuf,
                        const float* __restrict__ c2as, const float* __restrict__ c2ad,
                        const int* __restrict__ ctrl, float* __restrict__ h2,
                        float* __restrict__ as2, float* __restrict__ ad2){
  int gid = blockIdx.x*blockDim.x + threadIdx.x;
  int sid = gid >> 5, o = gid & 31;
  bool act = sid < ctrl[0];
  float s = 0.f;
  if (act){
    const float* t = tbuf + (size_t)sid*96;
    const float* wr = c2W + o*96;
    #pragma unroll
    for (int j = 0; j < 96; ++j) s = fmaf(wr[j], t[j], s);
    h2[(size_t)sid*32 + o] = s;
  }
  float a = act ? s*c2as[o] : 0.f;
  float b = act ? s*c2ad[o] : 0.f;
  #pragma unroll
  for (int w = 16; w >= 1; w >>= 1){
    a += __shfl_xor(a, w, 32);
    b += __shfl_xor(b, w, 32);
  }
  if (act && o == 0){ as2[sid] = a; ad2[sid] = b; }
}

// ---- layer-2 GAT agg at robots + concat + fc1 + tanh ----
__global__ void k_gat2fc1(const float* __restrict__ h2, const float* __restrict__ as2,
                          const float* __restrict__ ad2, const float* __restrict__ c2b,
                          const float* __restrict__ rf, const float* __restrict__ fc1W,
                          const float* __restrict__ fc1b, const int* __restrict__ sidx,
                          const int* __restrict__ cnt1, const int* __restrict__ csr1,
                          float* __restrict__ xs, int B){
  int rp = blockIdx.x*blockDim.x + threadIdx.x;
  if (rp >= B) return;
  float ad = ad2[rp];
  float den = 0.f, agg[32];
  #pragma unroll
  for (int o = 0; o < 32; ++o) agg[o] = 0.f;
  int beg = rp*DEG, n = cnt1[rp];
  n = (n < DEG) ? n : DEG;
  for (int j = -1; j < n; ++j){
    int ss;
    if (j < 0) ss = rp;                    // self loop (robot's own sid == rp)
    else { int s = csr1[beg + j]; ss = sidx[s]; if (ss < 0 || ss >= S2CAP) continue; }
    float wgt = attw(as2[ss] + ad);
    den += wgt;
    const float* hv = h2 + (size_t)ss*32;
    #pragma unroll
    for (int o = 0; o < 32; ++o) agg[o] = fmaf(wgt, hv[o], agg[o]);
  }
  float inv = 1.f/den;
  float cat[36];
  #pragma unroll
  for (int o = 0; o < 32; ++o) cat[o] = agg[o]*inv + c2b[o];
  #pragma unroll
  for (int k = 0; k < 4; ++k) cat[32+k] = rf[rp*4+k];
  for (int o = 0; o < 64; ++o){
    float s = fc1b[o];
    const float* wrow = fc1W + o*36;
    #pragma unroll
    for (int j = 0; j < 36; ++j) s = fmaf(wrow[j], cat[j], s);
    xs[(size_t)rp*64 + o] = ftanh(s);
  }
}

// ---- GRU input gates for all steps + whh transpose, fused ----
__global__ void k_giT(const float* __restrict__ xs, const float* __restrict__ wih,
                      const float* __restrict__ bih, const float* __restrict__ bhh,
                      float* __restrict__ gi, const float* __restrict__ whh,
                      float* __restrict__ whhT, int B){
  int gid = blockIdx.x*blockDim.x + threadIdx.x;
  int NGI = B*192;
  if (gid < NGI){
    int t = gid/192, g = gid - t*192;
    const float* xv = xs + (size_t)t*64;
    const float* wr = wih + (size_t)g*64;
    float s = bih[g] + (g < 128 ? bhh[g] : 0.f);
    #pragma unroll
    for (int k = 0; k < 64; ++k) s = fmaf(wr[k], xv[k], s);
    gi[gid] = s;
  } else {
    int q = gid - NGI;
    if (q < 192*64){
      int g = q >> 6, k = q & 63;
      whhT[k*192 + g] = whh[g*64 + k];
    }
  }
}

// ---- sequential GRU: 3 waves (r/z/n gate blocks), 64 weights/lane,
//      readlane h-broadcast, double-buffered LDS staging, 1 barrier/step,
//      redundant activation in all waves keeps h lane-resident ----
__global__ __launch_bounds__(192, 1) void k_gru3(const float* __restrict__ gi,
                       const float* __restrict__ whhT, const float* __restrict__ bhh,
                       float* __restrict__ ys, int B){
  int tid = threadIdx.x;
  int w = tid >> 6, u = tid & 63, g = tid;      // g = gate-row index in [0,192)
  float wv[64];
  #pragma unroll
  for (int k = 0; k < 64; ++k) wv[k] = whhT[k*192 + g];
  float bb = (w == 2) ? bhh[128 + u] : 0.f;     // bhh_n folded into staged an
  __shared__ float rzbuf[2][256];
  float hvec = 0.f;                              // lane u holds h[u] (all waves)
  float gcur = gi[g];
  for (int t = 0; t < B; ++t){
    int tn = (t + 1 < B) ? t + 1 : t;
    float gnext = gi[tn*192 + g];
    // dot_g = sum_k whh[g][k] * h[k], h broadcast via readlane
    float a0 = 0.f, a1 = 0.f, a2 = 0.f, a3 = 0.f;
    int hb = __float_as_int(hvec);
    #pragma unroll
    for (int k = 0; k < 64; k += 4){
      float h0 = __int_as_float(__builtin_amdgcn_readlane(hb, k));
      float h1 = __int_as_float(__builtin_amdgcn_readlane(hb, k + 1));
      float h2 = __int_as_float(__builtin_amdgcn_readlane(hb, k + 2));
      float h3 = __int_as_float(__builtin_amdgcn_readlane(hb, k + 3));
      a0 = fmaf(wv[k],     h0, a0);
      a1 = fmaf(wv[k + 1], h1, a1);
      a2 = fmaf(wv[k + 2], h2, a2);
      a3 = fmaf(wv[k + 3], h3, a3);
    }
    float dot = (a0 + a1) + (a2 + a3);
    float* buf = rzbuf[t & 1];
    if (w < 2){
      buf[w*64 + u] = gcur + dot;               // full pre-activation of r / z
    } else {
      buf[128 + u] = dot + bb;                  // an (recurrent n-term + bhh_n)
      buf[192 + u] = gcur;                      // i_n (input n-term)
    }
    __syncthreads();
    float pre_r = buf[u], pre_z = buf[64 + u], an = buf[128 + u], i_n = buf[192 + u];
    float r  = fsig(pre_r);
    float z  = fsig(pre_z);
    float ng = ftanh(i_n + r*an);
    float hnew = (1.f - z)*ng + z*hvec;
    if (w == 2) ys[(size_t)t*64 + u] = hnew;
    hvec = hnew;
    gcur = gnext;
  }
}

// ---- final fc2 ----
__global__ void k_fc2(const float* __restrict__ ys, const float* __restrict__ f2W,
                      const float* __restrict__ f2b, float* __restrict__ out, int B){
  int gid = blockIdx.x*blockDim.x + threadIdx.x;
  if (gid >= B*11) return;
  int t = gid/11, a = gid - t*11;
  const float* hv = ys + (size_t)t*64;
  const float* wr = f2W + a*64;
  float s = f2b[a];
  #pragma unroll
  for (int k = 0; k < 64; ++k) s = fmaf(wr[k], hv[k], s);
  out[gid] = s;
}

extern "C" void kernel_launch(void* const* d_in, const int* in_sizes, int n_in,
                              void* d_out, int out_size, void* d_ws, size_t ws_size,
                              hipStream_t stream) {
  (void)n_in; (void)out_size; (void)ws_size;
  const float* x    = (const float*)d_in[0];
  const int*   ei   = (const int*)d_in[1];
  const int*   rix  = (const int*)d_in[2];
  const float* rf   = (const float*)d_in[3];
  const float* c1W  = (const float*)d_in[4];
  const float* c1as = (const float*)d_in[5];
  const float* c1ad = (const float*)d_in[6];
  const float* c1b  = (const float*)d_in[7];
  const float* c2W  = (const float*)d_in[8];
  const float* c2as = (const float*)d_in[9];
  const float* c2ad = (const float*)d_in[10];
  const float* c2b  = (const float*)d_in[11];
  const float* fc1W = (const float*)d_in[12];
  const float* fc1b = (const float*)d_in[13];
  const float* wih  = (const float*)d_in[14];
  const float* whh  = (const float*)d_in[15];
  const float* bih  = (const float*)d_in[16];
  const float* bhh  = (const float*)d_in[17];
  const float* f2W  = (const float*)d_in[18];
  const float* f2b  = (const float*)d_in[19];
  float* out = (float*)d_out;

  const int N = in_sizes[0]/4;
  const int E = in_sizes[1]/2;
  const int B = in_sizes[2];

  char* w = (char*)d_ws;
  size_t off = 0;
  auto take = [&](size_t bytes)->char*{
    char* p = w + off;
    off = (off + bytes + 255) & ~(size_t)255;
    return p;
  };
  int*   ctrl   = (int*)  take(256);
  float* AsAd   = (float*)take(256);
  int*   sidx   = (int*)  take((size_t)N*4);
  int*   nodeof = (int*)  take((size_t)S2CAP*4);
  int*   cnt1   = (int*)  take((size_t)S2CAP*4);
  int*   csr1   = (int*)  take((size_t)S2CAP*DEG*4);
  float* tbuf   = (float*)take((size_t)S2CAP*96*4);
  float* h2     = (float*)take((size_t)S2CAP*32*4);
  float* as2    = (float*)take((size_t)S2CAP*4);
  float* ad2    = (float*)take((size_t)S2CAP*4);
  float* xs     = (float*)take((size_t)B*64*4);
  float* gi     = (float*)take((size_t)B*192*4);
  float* whhT   = (float*)take((size_t)192*64*4);
  float* ys     = (float*)take((size_t)B*64*4);

  hipMemsetAsync(sidx, 0xFF, (size_t)N*4, stream);       // -1

  k_init   <<<(S2CAP+255)/256, 256, 0, stream>>>(c1W, c1as, c1ad, AsAd, rix, B, sidx, nodeof, ctrl, cnt1);
  k_claim  <<<(E+255)/256, 256, 0, stream>>>(ei, E, B, sidx, nodeof, ctrl);
  k_scat   <<<(E+255)/256, 256, 0, stream>>>(ei, E, sidx, cnt1, csr1);
  k_gat1   <<<(S2CAP*6+255)/256, 256, 0, stream>>>(x, c1W, c1b, AsAd, nodeof, cnt1, csr1, ctrl, tbuf);
  k_h2att  <<<(S2CAP*32+255)/256, 256, 0, stream>>>(c2W, tbuf, c2as, c2ad, ctrl, h2, as2, ad2);
  k_gat2fc1<<<(B+255)/256, 256, 0, stream>>>(h2, as2, ad2, c2b, rf, fc1W, fc1b, sidx, cnt1, csr1, xs, B);
  k_giT    <<<(B*192 + 192*64 + 255)/256, 256, 0, stream>>>(xs, wih, bih, bhh, gi, whh, whhT, B);
  k_gru3   <<<1, 192, 0, stream>>>(gi, whhT, bhh, ys, B);
  k_fc2    <<<(B*11+255)/256, 256, 0, stream>>>(ys, f2W, f2b, out, B);
}

// Round 4
// 949.317 us; speedup vs baseline: 1.1394x; 1.0053x over previous
//
#include <hip/hip_runtime.h>

#define S2CAP 24576   // cap on |S2| (robots + sources of robot in-edges); expected ~17.4K
#define DEG   96      // padded per-node in-degree cap (Poisson(16): P(>96) ~ 1e-40)

__device__ __forceinline__ float fsig(float x){ return 1.f/(1.f + __expf(-x)); }
__device__ __forceinline__ float ftanh(float a){
  a = fminf(fmaxf(a, -15.f), 15.f);
  float e2 = __expf(2.f*a);
  return (e2 - 1.f)/(e2 + 1.f);
}
__device__ __forceinline__ float attw(float e){        // leaky_relu(0.2) then exp (no max-sub)
  e = (e > 0.f) ? e : 0.2f*e;
  return __expf(e);
}

// ---- fused init: AsAd precompute + robot flag + cnt1 zero + ctrl ----
// (sidx was memset to -1 earlier in the stream)
__global__ void k_init(const float* __restrict__ c1W, const float* __restrict__ c1as,
                       const float* __restrict__ c1ad, float* __restrict__ AsAd,
                       const int* __restrict__ rix, int B, int* __restrict__ sidx,
                       int* __restrict__ nodeof, int* __restrict__ ctrl,
                       int* __restrict__ cnt1){
  int gid = blockIdx.x*blockDim.x + threadIdx.x;
  if (gid == 0) ctrl[0] = B;
  if (gid < 48){
    int which = gid/24, r = gid%24, k = r/6, h = r%6;
    const float* av = which ? c1ad : c1as;
    float s = 0.f;
    for (int f = 0; f < 16; ++f) s += c1W[(h*16+f)*4 + k] * av[h*16+f];
    AsAd[which*24 + k*6 + h] = s;
  }
  if (gid < B){ int r = rix[gid]; sidx[r] = gid; nodeof[gid] = r; }
  if (gid < S2CAP) cnt1[gid] = 0;
}

// ---- scan 1: claim sources of edges into robots ----
__global__ void k_claim(const int* __restrict__ ei, int E, int B,
                        int* __restrict__ sidx, int* __restrict__ nodeof,
                        int* __restrict__ ctrl){
  int e = blockIdx.x*blockDim.x + threadIdx.x;
  if (e >= E) return;
  int d = ei[E + e];
  int sd = sidx[d];
  if (sd < 0 || sd >= B) return;           // dst not a robot
  int s = ei[e];
  if (sidx[s] < 0){
    int old = atomicCAS(&sidx[s], -1, -2);
    if (old == -1){
      int id = atomicAdd(&ctrl[0], 1);
      if (id < S2CAP){ nodeof[id] = s; sidx[s] = id; }
      else sidx[s] = -1;                    // overflow (won't happen at these sizes)
    }
  }
}

// ---- scan 2: scatter sources into fixed-stride padded CSR (no count/scan passes) ----
__global__ void k_scat(const int* __restrict__ ei, int E,
                       const int* __restrict__ sidx, int* __restrict__ cnt1,
                       int* __restrict__ csr1){
  int e = blockIdx.x*blockDim.x + threadIdx.x;
  if (e >= E) return;
  int sd = sidx[ei[E + e]];
  if (sd >= 0){
    int p = atomicAdd(&cnt1[sd], 1);
    if (p < DEG) csr1[sd*DEG + p] = ei[e];
  }
}

// ---- layer-1 GAT agg at S2 nodes, per (node, head); writes tanh(agg/den + b) ----
__global__ void k_gat1(const float* __restrict__ x, const float* __restrict__ c1W,
                       const float* __restrict__ c1b, const float* __restrict__ AsAd,
                       const int* __restrict__ nodeof, const int* __restrict__ cnt1,
                       const int* __restrict__ csr1, const int* __restrict__ ctrl,
                       float* __restrict__ tbuf){
  int gid = blockIdx.x*blockDim.x + threadIdx.x;
  int sid = gid/6, h = gid - sid*6;
  if (sid >= ctrl[0]) return;
  float Ask[4], Adk[4];
  #pragma unroll
  for (int k = 0; k < 4; ++k){ Ask[k] = AsAd[k*6+h]; Adk[k] = AsAd[24 + k*6 + h]; }
  float W[16][4];
  #pragma unroll
  for (int f = 0; f < 16; ++f)
    #pragma unroll
    for (int k = 0; k < 4; ++k) W[f][k] = c1W[(h*16+f)*4 + k];
  int d = nodeof[sid];
  float4 xd = *(const float4*)(x + 4*(size_t)d);
  float ad = xd.x*Adk[0] + xd.y*Adk[1] + xd.z*Adk[2] + xd.w*Adk[3];
  int beg = sid*DEG, n = cnt1[sid];
  n = (n < DEG) ? n : DEG;
  float den = 0.f, agg[16];
  #pragma unroll
  for (int f = 0; f < 16; ++f) agg[f] = 0.f;
  for (int j = -1; j < n; ++j){            // j==-1: self loop
    int s = (j < 0) ? d : csr1[beg + j];
    float4 xv = *(const float4*)(x + 4*(size_t)s);
    float as = xv.x*Ask[0] + xv.y*Ask[1] + xv.z*Ask[2] + xv.w*Ask[3];
    float wgt = attw(as + ad);
    den += wgt;
    #pragma unroll
    for (int f = 0; f < 16; ++f){
      float h1 = xv.x*W[f][0] + xv.y*W[f][1] + xv.z*W[f][2] + xv.w*W[f][3];
      agg[f] = fmaf(wgt, h1, agg[f]);
    }
  }
  float inv = 1.f/den;
  #pragma unroll
  for (int f = 0; f < 16; ++f)
    tbuf[(size_t)sid*96 + h*16 + f] = ftanh(agg[f]*inv + c1b[h*16+f]);
}

// ---- layer-2 linear + attention scalars fused (32-lane shfl reduce) ----
__global__ void k_h2att(const float* __restrict__ c2W, const float* __restrict__ tbuf,
                        const float* __restrict__ c2as, const float* __restrict__ c2ad,
                        const int* __restrict__ ctrl, float* __restrict__ h2,
                        float* __restrict__ as2, float* __restrict__ ad2){
  int gid = blockIdx.x*blockDim.x + threadIdx.x;
  int sid = gid >> 5, o = gid & 31;
  bool act = sid < ctrl[0];
  float s = 0.f;
  if (act){
    const float* t = tbuf + (size_t)sid*96;
    const float* wr = c2W + o*96;
    #pragma unroll
    for (int j = 0; j < 96; ++j) s = fmaf(wr[j], t[j], s);
    h2[(size_t)sid*32 + o] = s;
  }
  float a = act ? s*c2as[o] : 0.f;
  float b = act ? s*c2ad[o] : 0.f;
  #pragma unroll
  for (int w = 16; w >= 1; w >>= 1){
    a += __shfl_xor(a, w, 32);
    b += __shfl_xor(b, w, 32);
  }
  if (act && o == 0){ as2[sid] = a; ad2[sid] = b; }
}

// ---- layer-2 GAT agg at robots + concat + fc1 + tanh ----
__global__ void k_gat2fc1(const float* __restrict__ h2, const float* __restrict__ as2,
                          const float* __restrict__ ad2, const float* __restrict__ c2b,
                          const float* __restrict__ rf, const float* __restrict__ fc1W,
                          const float* __restrict__ fc1b, const int* __restrict__ sidx,
                          const int* __restrict__ cnt1, const int* __restrict__ csr1,
                          float* __restrict__ xs, int B){
  int rp = blockIdx.x*blockDim.x + threadIdx.x;
  if (rp >= B) return;
  float ad = ad2[rp];
  float den = 0.f, agg[32];
  #pragma unroll
  for (int o = 0; o < 32; ++o) agg[o] = 0.f;
  int beg = rp*DEG, n = cnt1[rp];
  n = (n < DEG) ? n : DEG;
  for (int j = -1; j < n; ++j){
    int ss;
    if (j < 0) ss = rp;                    // self loop (robot's own sid == rp)
    else { int s = csr1[beg + j]; ss = sidx[s]; if (ss < 0 || ss >= S2CAP) continue; }
    float wgt = attw(as2[ss] + ad);
    den += wgt;
    const float* hv = h2 + (size_t)ss*32;
    #pragma unroll
    for (int o = 0; o < 32; ++o) agg[o] = fmaf(wgt, hv[o], agg[o]);
  }
  float inv = 1.f/den;
  float cat[36];
  #pragma unroll
  for (int o = 0; o < 32; ++o) cat[o] = agg[o]*inv + c2b[o];
  #pragma unroll
  for (int k = 0; k < 4; ++k) cat[32+k] = rf[rp*4+k];
  for (int o = 0; o < 64; ++o){
    float s = fc1b[o];
    const float* wrow = fc1W + o*36;
    #pragma unroll
    for (int j = 0; j < 36; ++j) s = fmaf(wrow[j], cat[j], s);
    xs[(size_t)rp*64 + o] = ftanh(s);
  }
}

// ---- GRU input gates for all steps + whh transpose, fused ----
__global__ void k_giT(const float* __restrict__ xs, const float* __restrict__ wih,
                      const float* __restrict__ bih, const float* __restrict__ bhh,
                      float* __restrict__ gi, const float* __restrict__ whh,
                      float* __restrict__ whhT, int B){
  int gid = blockIdx.x*blockDim.x + threadIdx.x;
  int NGI = B*192;
  if (gid < NGI){
    int t = gid/192, g = gid - t*192;
    const float* xv = xs + (size_t)t*64;
    const float* wr = wih + (size_t)g*64;
    float s = bih[g] + (g < 128 ? bhh[g] : 0.f);
    #pragma unroll
    for (int k = 0; k < 64; ++k) s = fmaf(wr[k], xv[k], s);
    gi[gid] = s;
  } else {
    int q = gid - NGI;
    if (q < 192*64){
      int g = q >> 6, k = q & 63;
      whhT[k*192 + g] = whh[g*64 + k];
    }
  }
}

// ---- sequential GRU: 3 waves (r/z/n gate blocks), 64 weights/lane pinned in
//      VGPRs (per-iteration asm pin defeats load rematerialization),
//      readlane h-broadcast, double-buffered LDS staging, 1 barrier/step ----
__global__ __launch_bounds__(192, 1) void k_gru3(const float* __restrict__ gi,
                       const float* __restrict__ whhT, const float* __restrict__ bhh,
                       float* __restrict__ ys, int B){
  int tid = threadIdx.x;
  int w = tid >> 6, u = tid & 63, g = tid;      // g = gate-row index in [0,192)
  float wv[64];
  #pragma unroll
  for (int k = 0; k < 64; ++k) wv[k] = whhT[k*192 + g];
  float bb = (w == 2) ? bhh[128 + u] : 0.f;     // bhh_n folded into staged an
  __shared__ float rzbuf[2][256];
  float hvec = 0.f;                              // lane u holds h[u] (all waves)
  float gcur = gi[g];
  for (int t = 0; t < B; ++t){
    // Pin the weights in VGPRs EVERY iteration: the (empty) asm nominally
    // writes wv[k], so the compiler cannot re-materialize the whhT loads
    // inside the loop — they must stay register-resident across all steps.
    #pragma unroll
    for (int k = 0; k < 64; ++k) asm volatile("" : "+v"(wv[k]));
    int tn = (t + 1 < B) ? t + 1 : t;
    float gnext = gi[tn*192 + g];
    // dot_g = sum_k whh[g][k] * h[k], h broadcast via readlane
    float a0 = 0.f, a1 = 0.f, a2 = 0.f, a3 = 0.f;
    int hb = __float_as_int(hvec);
    #pragma unroll
    for (int k = 0; k < 64; k += 4){
      float h0 = __int_as_float(__builtin_amdgcn_readlane(hb, k));
      float h1 = __int_as_float(__builtin_amdgcn_readlane(hb, k + 1));
      float h2 = __int_as_float(__builtin_amdgcn_readlane(hb, k + 2));
      float h3 = __int_as_float(__builtin_amdgcn_readlane(hb, k + 3));
      a0 = fmaf(wv[k],     h0, a0);
      a1 = fmaf(wv[k + 1], h1, a1);
      a2 = fmaf(wv[k + 2], h2, a2);
      a3 = fmaf(wv[k + 3], h3, a3);
    }
    float dot = (a0 + a1) + (a2 + a3);
    float* buf = rzbuf[t & 1];
    if (w < 2){
      buf[w*64 + u] = gcur + dot;               // full pre-activation of r / z
    } else {
      buf[128 + u] = dot + bb;                  // an (recurrent n-term + bhh_n)
      buf[192 + u] = gcur;                      // i_n (input n-term)
    }
    __syncthreads();
    float pre_r = buf[u], pre_z = buf[64 + u], an = buf[128 + u], i_n = buf[192 + u];
    float r  = fsig(pre_r);
    float z  = fsig(pre_z);
    float ng = ftanh(i_n + r*an);
    float hnew = (1.f - z)*ng + z*hvec;
    if (w == 2) ys[(size_t)t*64 + u] = hnew;
    hvec = hnew;
    gcur = gnext;
  }
}

// ---- final fc2 ----
__global__ void k_fc2(const float* __restrict__ ys, const float* __restrict__ f2W,
                      const float* __restrict__ f2b, float* __restrict__ out, int B){
  int gid = blockIdx.x*blockDim.x + threadIdx.x;
  if (gid >= B*11) return;
  int t = gid/11, a = gid - t*11;
  const float* hv = ys + (size_t)t*64;
  const float* wr = f2W + a*64;
  float s = f2b[a];
  #pragma unroll
  for (int k = 0; k < 64; ++k) s = fmaf(wr[k], hv[k], s);
  out[gid] = s;
}

extern "C" void kernel_launch(void* const* d_in, const int* in_sizes, int n_in,
                              void* d_out, int out_size, void* d_ws, size_t ws_size,
                              hipStream_t stream) {
  (void)n_in; (void)out_size; (void)ws_size;
  const float* x    = (const float*)d_in[0];
  const int*   ei   = (const int*)d_in[1];
  const int*   rix  = (const int*)d_in[2];
  const float* rf   = (const float*)d_in[3];
  const float* c1W  = (const float*)d_in[4];
  const float* c1as = (const float*)d_in[5];
  const float* c1ad = (const float*)d_in[6];
  const float* c1b  = (const float*)d_in[7];
  const float* c2W  = (const float*)d_in[8];
  const float* c2as = (const float*)d_in[9];
  const float* c2ad = (const float*)d_in[10];
  const float* c2b  = (const float*)d_in[11];
  const float* fc1W = (const float*)d_in[12];
  const float* fc1b = (const float*)d_in[13];
  const float* wih  = (const float*)d_in[14];
  const float* whh  = (const float*)d_in[15];
  const float* bih  = (const float*)d_in[16];
  const float* bhh  = (const float*)d_in[17];
  const float* f2W  = (const float*)d_in[18];
  const float* f2b  = (const float*)d_in[19];
  float* out = (float*)d_out;

  const int N = in_sizes[0]/4;
  const int E = in_sizes[1]/2;
  const int B = in_sizes[2];

  char* w = (char*)d_ws;
  size_t off = 0;
  auto take = [&](size_t bytes)->char*{
    char* p = w + off;
    off = (off + bytes + 255) & ~(size_t)255;
    return p;
  };
  int*   ctrl   = (int*)  take(256);
  float* AsAd   = (float*)take(256);
  int*   sidx   = (int*)  take((size_t)N*4);
  int*   nodeof = (int*)  take((size_t)S2CAP*4);
  int*   cnt1   = (int*)  take((size_t)S2CAP*4);
  int*   csr1   = (int*)  take((size_t)S2CAP*DEG*4);
  float* tbuf   = (float*)take((size_t)S2CAP*96*4);
  float* h2     = (float*)take((size_t)S2CAP*32*4);
  float* as2    = (float*)take((size_t)S2CAP*4);
  float* ad2    = (float*)take((size_t)S2CAP*4);
  float* xs     = (float*)take((size_t)B*64*4);
  float* gi     = (float*)take((size_t)B*192*4);
  float* whhT   = (float*)take((size_t)192*64*4);
  float* ys     = (float*)take((size_t)B*64*4);

  hipMemsetAsync(sidx, 0xFF, (size_t)N*4, stream);       // -1

  k_init   <<<(S2CAP+255)/256, 256, 0, stream>>>(c1W, c1as, c1ad, AsAd, rix, B, sidx, nodeof, ctrl, cnt1);
  k_claim  <<<(E+255)/256, 256, 0, stream>>>(ei, E, B, sidx, nodeof, ctrl);
  k_scat   <<<(E+255)/256, 256, 0, stream>>>(ei, E, sidx, cnt1, csr1);
  k_gat1   <<<(S2CAP*6+255)/256, 256, 0, stream>>>(x, c1W, c1b, AsAd, nodeof, cnt1, csr1, ctrl, tbuf);
  k_h2att  <<<(S2CAP*32+255)/256, 256, 0, stream>>>(c2W, tbuf, c2as, c2ad, ctrl, h2, as2, ad2);
  k_gat2fc1<<<(B+255)/256, 256, 0, stream>>>(h2, as2, ad2, c2b, rf, fc1W, fc1b, sidx, cnt1, csr1, xs, B);
  k_giT    <<<(B*192 + 192*64 + 255)/256, 256, 0, stream>>>(xs, wih, bih, bhh, gi, whh, whhT, B);
  k_gru3   <<<1, 192, 0, stream>>>(gi, whhT, bhh, ys, B);
  k_fc2    <<<(B*11+255)/256, 256, 0, stream>>>(ys, f2W, f2b, out, B);
}